// Round 1
// 209.505 us; speedup vs baseline: 1.0148x; 1.0148x over previous
//
#include <hip/hip_runtime.h>

// YOLOv1 loss: 802816 rows x 30 f32, two tensors, scalar out.
// R7: R6's 2.6 TB/s plateau was a vector-memory REQUEST-RATE wall, not a
// latency/outstanding problem: per-row threads make every load a 64-lane
// gather at 120B stride (8 useful B per request; 24.1M requests / 75us =
// 1.25 req/cy/CU). Fix: coalesced staging. Each block's 256 rows are
// 30720 contiguous bytes per tensor; stage with lane-contiguous dwordx4
// (7x16B + 1x8B per thread per tensor, in one asm block with trailing
// vmcnt(0) so all 16 loads stay in flight), write linearly to LDS,
// barrier, then each thread reads its own row from LDS.
//   - LDS row reads: stride 30 dwords -> 4 dwords/bank per b64 wave read
//     = the 128-dword minimum, effectively conflict-free.
//   - LDS 61.5KB/block -> 2 blocks/CU (8 waves); 16 coalesced loads in
//     flight per wave covers the miss latency at the 10 B/cy/CU HBM share.

#define COLS 30
#define NB   3136              // 802816 rows / 256 rows per K1 block

typedef float f32x4 __attribute__((ext_vector_type(4)));
typedef float f32x2 __attribute__((ext_vector_type(2)));

// ---------------- per-row math on named scalars (bit-exact) ---------------
#define ROW_MATH_BODY                                                        \
    const float C = 1.0f / 7.0f;                                             \
    float conf = b2.x;                    /* T[4], exactly 0.0 or 1.0 */     \
    coord = (conf == 1.0f);                                                  \
    noo = 0.0f;                                                              \
    if (conf == 0.0f) {                                                      \
        float d4_ = a2.x - conf;                                             \
        float d9_ = a4.y - b4.y;                                             \
        noo = d4_ * d4_ + d9_ * d9_;                                         \
    }                                                                        \
    float T0 = b0.x, T1 = b0.y, T2v = b1.x, T3 = b1.y;                       \
    float tb0 = T0 * T0, tb1 = T1 * T1, tb2 = T2v * T2v, tb3 = T3 * T3;      \
    float tax = tb0 * C - tb2, tay = tb1 * C - tb3;                          \
    float tbx = tax * C + tb2, tby = tay * C + tb3;                          \
    float areaT = (tbx - tax) * (tby - tay);                                 \
    float pax0 = a0.x * C - a1.x, pay0 = a0.y * C - a1.y;                    \
    float pbx0 = pax0 * C + a1.x, pby0 = pay0 * C + a1.y;                    \
    float pax1 = a2.y * C - a3.y, pay1 = a3.x * C - a4.x;                    \
    float pbx1 = pax1 * C + a3.y, pby1 = pay1 * C + a4.x;                    \
    float ltx = fmaxf(pax0, tax), lty = fmaxf(pay0, tay);                    \
    float rbx = fminf(pbx0, tbx), rby = fminf(pby0, tby);                    \
    float wx = fmaxf(rbx - ltx, 0.0f), wy = fmaxf(rby - lty, 0.0f);          \
    float inter = wx * wy;                                                   \
    float areaP = (pbx0 - pax0) * (pby0 - pay0);                             \
    float iou0 = inter / (areaP + areaT - inter);                            \
    ltx = fmaxf(pax1, tax); lty = fmaxf(pay1, tay);                          \
    rbx = fminf(pbx1, tbx); rby = fminf(pby1, tby);                          \
    wx = fmaxf(rbx - ltx, 0.0f); wy = fmaxf(rby - lty, 0.0f);                \
    inter = wx * wy;                                                         \
    areaP = (pbx1 - pax1) * (pby1 - pay1);                                   \
    float iou1 = inter / (areaP + areaT - inter);                            \
    int idx = (iou1 > iou0) ? 1 : 0;      /* argmax, first on ties */        \
    float sx = idx ? a2.y : a0.x;                                            \
    float sy = idx ? a3.x : a0.y;                                            \
    float sw = idx ? a3.y : a1.x;                                            \
    float sh = idx ? a4.x : a1.y;                                            \
    float best = b5.x, pc = a5.x;         /* class argmax, strict > */       \
    CLS_STEP(b5.y,  a5.y)  CLS_STEP(b6.x,  a6.x)  CLS_STEP(b6.y,  a6.y)      \
    CLS_STEP(b7.x,  a7.x)  CLS_STEP(b7.y,  a7.y)  CLS_STEP(b8.x,  a8.x)      \
    CLS_STEP(b8.y,  a8.y)  CLS_STEP(b9.x,  a9.x)  CLS_STEP(b9.y,  a9.y)      \
    CLS_STEP(b10.x, a10.x) CLS_STEP(b10.y, a10.y) CLS_STEP(b11.x, a11.x)     \
    CLS_STEP(b11.y, a11.y) CLS_STEP(b12.x, a12.x) CLS_STEP(b12.y, a12.y)     \
    CLS_STEP(b13.x, a13.x) CLS_STEP(b13.y, a13.y) CLS_STEP(b14.x, a14.x)     \
    CLS_STEP(b14.y, a14.y)                                                   \
    float d0 = sx - T0, d1 = sy - T1, d2 = sw - T2v, d3 = sh - T3;           \
    float dc = pc - 1.0f;                                                    \
    r = d0 * d0 + d1 * d1 + d2 * d2 + d3 * d3 + 2.0f * dc * dc;

#define CLS_STEP(tv, pv) { float v_ = (tv); if (v_ > best) { best = v_; pc = (pv); } }

__device__ __forceinline__ void row_compute_vals(
    float2 a0, float2 a1, float2 a2, float2 a3, float2 a4,
    float2 a5, float2 a6, float2 a7, float2 a8, float2 a9,
    float2 a10, float2 a11, float2 a12, float2 a13, float2 a14,
    float2 b0, float2 b1, float2 b2, float2 b3, float2 b4,
    float2 b5, float2 b6, float2 b7, float2 b8, float2 b9,
    float2 b10, float2 b11, float2 b12, float2 b13, float2 b14,
    bool& coord, float& r, float& noo)
{
    ROW_MATH_BODY
}

// Plain-C++ row load+compute (used only in K2's 256-row fixup).
__device__ __forceinline__ void row_load_compute(
    const float* __restrict__ gp, const float* __restrict__ gt, long row,
    bool& coord, float& r, float& noo)
{
    const float2* P2 = (const float2*)(gp + row * (long)COLS);
    const float2* T2 = (const float2*)(gt + row * (long)COLS);
    float2 a0 = P2[0],  a1 = P2[1],  a2 = P2[2],  a3 = P2[3],  a4 = P2[4];
    float2 a5 = P2[5],  a6 = P2[6],  a7 = P2[7],  a8 = P2[8],  a9 = P2[9];
    float2 a10 = P2[10], a11 = P2[11], a12 = P2[12], a13 = P2[13], a14 = P2[14];
    float2 b0 = T2[0],  b1 = T2[1],  b2 = T2[2],  b3 = T2[3],  b4 = T2[4];
    float2 b5 = T2[5],  b6 = T2[6],  b7 = T2[7],  b8 = T2[8],  b9 = T2[9];
    float2 b10 = T2[10], b11 = T2[11], b12 = T2[12], b13 = T2[13], b14 = T2[14];
    ROW_MATH_BODY
}

// K1: per-block (256 rows) {coord count, sum coord r, noobj sum}.
// Coalesced global stage -> LDS (linear layout) -> per-row LDS reads.
__global__ __launch_bounds__(256, 2) void yolo_k1(const float* __restrict__ gp,
                                                  const float* __restrict__ gt,
                                                  int* __restrict__ cnt,
                                                  float* __restrict__ sumR,
                                                  float* __restrict__ noo) {
    __shared__ f32x4 ldsP[1920];   // 256 rows x 30 f32 = 30720 B, linear
    __shared__ f32x4 ldsT[1920];
    __shared__ float wr[4], wn[4];
    __shared__ int wc[4];
    int tid = threadIdx.x;

    // Per-block contiguous region: 30720 B per tensor.
    long gbase = (long)blockIdx.x * (256L * COLS);     // float index
    const float* gpb = gp + gbase;
    const float* gtb = gt + gbase;

    // Thread tid covers float4 chunks {r*256+tid : r=0..6} (bytes r*4096 +
    // tid*16) + float2 tail chunk 3584+tid (byte 28672 + tid*8), fully
    // coalesced across the wave. 13-bit signed imm can't span 4096, so use
    // bases at odd multiples of 4096 with offset:-4096 / 0.
    unsigned o0 = (unsigned)tid * 16u + 4096u;
    unsigned o1 = (unsigned)tid * 16u + 12288u;
    unsigned o2 = (unsigned)tid * 16u + 20480u;
    unsigned o3 = (unsigned)tid * 16u + 24576u;
    unsigned o4 = (unsigned)tid * 8u  + 28672u;

    f32x4 p0, p1, p2, p3, p4, p5, p6; f32x2 p7;
    f32x4 t0, t1, t2, t3, t4, t5, t6; f32x2 t7;
    asm volatile(
        "global_load_dwordx4 %0,  %[o0], %[pb] offset:-4096\n\t"
        "global_load_dwordx4 %1,  %[o0], %[pb]\n\t"
        "global_load_dwordx4 %2,  %[o1], %[pb] offset:-4096\n\t"
        "global_load_dwordx4 %3,  %[o1], %[pb]\n\t"
        "global_load_dwordx4 %4,  %[o2], %[pb] offset:-4096\n\t"
        "global_load_dwordx4 %5,  %[o2], %[pb]\n\t"
        "global_load_dwordx4 %6,  %[o3], %[pb]\n\t"
        "global_load_dwordx2 %7,  %[o4], %[pb]\n\t"
        "global_load_dwordx4 %8,  %[o0], %[tb] offset:-4096\n\t"
        "global_load_dwordx4 %9,  %[o0], %[tb]\n\t"
        "global_load_dwordx4 %10, %[o1], %[tb] offset:-4096\n\t"
        "global_load_dwordx4 %11, %[o1], %[tb]\n\t"
        "global_load_dwordx4 %12, %[o2], %[tb] offset:-4096\n\t"
        "global_load_dwordx4 %13, %[o2], %[tb]\n\t"
        "global_load_dwordx4 %14, %[o3], %[tb]\n\t"
        "global_load_dwordx2 %15, %[o4], %[tb]\n\t"
        "s_waitcnt vmcnt(0)"
        : "=&v"(p0), "=&v"(p1), "=&v"(p2), "=&v"(p3), "=&v"(p4), "=&v"(p5),
          "=&v"(p6), "=&v"(p7),
          "=&v"(t0), "=&v"(t1), "=&v"(t2), "=&v"(t3), "=&v"(t4), "=&v"(t5),
          "=&v"(t6), "=&v"(t7)
        : [o0]"v"(o0), [o1]"v"(o1), [o2]"v"(o2), [o3]"v"(o3), [o4]"v"(o4),
          [pb]"s"(gpb), [tb]"s"(gtb)
        : "memory");

    // Linear LDS store (same layout as global) — sequential addresses per
    // wave, conflict-free b128/b64 writes.
    ldsP[0 * 256 + tid] = p0;  ldsP[1 * 256 + tid] = p1;
    ldsP[2 * 256 + tid] = p2;  ldsP[3 * 256 + tid] = p3;
    ldsP[4 * 256 + tid] = p4;  ldsP[5 * 256 + tid] = p5;
    ldsP[6 * 256 + tid] = p6;
    ldsT[0 * 256 + tid] = t0;  ldsT[1 * 256 + tid] = t1;
    ldsT[2 * 256 + tid] = t2;  ldsT[3 * 256 + tid] = t3;
    ldsT[4 * 256 + tid] = t4;  ldsT[5 * 256 + tid] = t5;
    ldsT[6 * 256 + tid] = t6;
    float* lpf = (float*)ldsP;
    float* ltf = (float*)ldsT;
    *(f32x2*)(lpf + 7168 + 2 * tid) = p7;
    *(f32x2*)(ltf + 7168 + 2 * tid) = t7;
    __syncthreads();

    // Row reads from LDS: stride 30 dwords -> banks uniformly 4 dwords each
    // per b64 wave read (the 128-dword minimum).
    const float2* P2 = (const float2*)(lpf + tid * COLS);
    const float2* T2 = (const float2*)(ltf + tid * COLS);
    float2 a0 = P2[0],  a1 = P2[1],  a2 = P2[2],  a3 = P2[3],  a4 = P2[4];
    float2 a5 = P2[5],  a6 = P2[6],  a7 = P2[7],  a8 = P2[8],  a9 = P2[9];
    float2 a10 = P2[10], a11 = P2[11], a12 = P2[12], a13 = P2[13], a14 = P2[14];
    float2 b0 = T2[0],  b1 = T2[1],  b2 = T2[2],  b3 = T2[3],  b4 = T2[4];
    float2 b5 = T2[5],  b6 = T2[6],  b7 = T2[7],  b8 = T2[8],  b9 = T2[9];
    float2 b10 = T2[10], b11 = T2[11], b12 = T2[12], b13 = T2[13], b14 = T2[14];

    bool coord; float r, nt;
    row_compute_vals(a0, a1, a2, a3, a4, a5, a6, a7, a8, a9,
                     a10, a11, a12, a13, a14,
                     b0, b1, b2, b3, b4, b5, b6, b7, b8, b9,
                     b10, b11, b12, b13, b14, coord, r, nt);
    float rl = coord ? r : 0.0f;

    unsigned long long bal = __ballot(coord);
    int c = (int)__popcll(bal);
#pragma unroll
    for (int off = 32; off > 0; off >>= 1) {
        rl += __shfl_down(rl, off);
        nt += __shfl_down(nt, off);
    }
    int wave = tid >> 6, lane = tid & 63;
    if (lane == 0) { wr[wave] = rl; wn[wave] = nt; wc[wave] = c; }
    __syncthreads();
    if (tid == 0) {
        cnt[blockIdx.x]  = wc[0] + wc[1] + wc[2] + wc[3];
        sumR[blockIdx.x] = wr[0] + wr[1] + wr[2] + wr[3];
        noo[blockIdx.x]  = wn[0] + wn[1] + wn[2] + wn[3];
    }
}

// K2: totals + scan + boundary-block fixup, single block (same as R4).
__global__ __launch_bounds__(256) void yolo_k2(const int* __restrict__ cnt,
                                               const float* __restrict__ sumR,
                                               const float* __restrict__ noo,
                                               const float* __restrict__ gp,
                                               const float* __restrict__ gt,
                                               float* __restrict__ out) {
    __shared__ int   wsum[4];
    __shared__ float wf[4], wn2[4];
    __shared__ int   s_bstar, s_kstar;
    __shared__ float s_base;
    __shared__ int   s_wcnt[4];
    int tid = threadIdx.x;
    int lane = tid & 63, wave = tid >> 6;
    if (tid == 0) { s_bstar = -1; s_kstar = 0; }

    const int PER = 13;                 // 256*13 = 3328 >= 3136
    int start = tid * PER;
    int end = min(NB, start + PER);

    int cloc = 0; float nloc = 0.0f;
    for (int i = start; i < end; ++i) { cloc += cnt[i]; nloc += noo[i]; }

    int incl = cloc;                    // inclusive shfl scan within wave
#pragma unroll
    for (int off = 1; off < 64; off <<= 1) {
        int v = __shfl_up(incl, off);
        if (lane >= off) incl += v;
    }
    if (lane == 63) wsum[wave] = incl;
    __syncthreads();                    // also orders s_bstar init vs walk
    int woff = 0;
#pragma unroll
    for (int w = 0; w < 4; ++w) woff += (w < wave) ? wsum[w] : 0;
    int ex = woff + incl - cloc;        // exclusive global prefix
    int n_obj = wsum[0] + wsum[1] + wsum[2] + wsum[3];
    int n_half = n_obj >> 1;

    float acc = 0.0f;
    int running = ex;
    for (int i = start; i < end; ++i) {
        int ci = cnt[i];
        if (ci > 0) {
            if (running + ci <= n_half) {
                acc += sumR[i];
            } else if (running < n_half) {  // exactly one thread ever
                s_bstar = i;
                s_kstar = n_half - running;
            }
        }
        running += ci;
    }

#pragma unroll
    for (int off = 32; off > 0; off >>= 1) {
        acc  += __shfl_down(acc, off);
        nloc += __shfl_down(nloc, off);
    }
    if (lane == 0) { wf[wave] = acc; wn2[wave] = nloc; }
    __syncthreads();
    if (tid == 0)
        s_base = 5.0f * (wf[0] + wf[1] + wf[2] + wf[3])
               + 0.5f * (wn2[0] + wn2[1] + wn2[2] + wn2[3]);
    __syncthreads();

    // Phase B: boundary block fixup (256 rows)
    int bstar = s_bstar, kstar = s_kstar;
    float total = 0.0f;
    if (bstar >= 0) {                    // uniform branch
        long row = (long)bstar * 256 + tid;
        bool coord; float r, nt;
        row_load_compute(gp, gt, row, coord, r, nt);
        unsigned long long bal = __ballot(coord);
        if (lane == 0) s_wcnt[wave] = (int)__popcll(bal);
        __syncthreads();
        int waveoff = 0;
#pragma unroll
        for (int w = 0; w < 4; ++w) waveoff += (w < wave) ? s_wcnt[w] : 0;
        unsigned long long below_incl =
            (lane == 63) ? bal : (bal & ((1ull << (lane + 1)) - 1ull));
        int rank = waveoff + (int)__popcll(below_incl);  // inclusive rank
        float val = (coord && rank <= kstar) ? r : 0.0f;
#pragma unroll
        for (int off = 32; off > 0; off >>= 1) val += __shfl_down(val, off);
        if (lane == 0) wf[wave] = val;
        __syncthreads();
        if (tid == 0) total = wf[0] + wf[1] + wf[2] + wf[3];
    }
    if (tid == 0) out[0] = s_base + 5.0f * total;
}

extern "C" void kernel_launch(void* const* d_in, const int* in_sizes, int n_in,
                              void* d_out, int out_size, void* d_ws, size_t ws_size,
                              hipStream_t stream) {
    (void)in_sizes; (void)n_in; (void)out_size; (void)ws_size;
    const float* p = (const float*)d_in[0];   // predictions
    const float* t = (const float*)d_in[1];   // targets
    char* ws = (char*)d_ws;                   // ~38 KB used
    int*   cnt  = (int*)ws;
    float* sumR = (float*)(ws + (size_t)NB * 4);
    float* noo  = (float*)(ws + (size_t)NB * 8);
    float* out  = (float*)d_out;

    yolo_k1<<<NB, 256, 0, stream>>>(p, t, cnt, sumR, noo);
    yolo_k2<<<1, 256, 0, stream>>>(cnt, sumR, noo, p, t, out);
}